// Round 9
// baseline (762.048 us; speedup 1.0000x reference)
//
#include <hip/hip_runtime.h>
#include <hip/hip_bf16.h>

// HQQ 4-bit linear: out = x @ dequant(W_q)^T + bias
// M=B*S=4096, K=4096, N=4096, GROUP=128. fp16 reference arrays arrive as FP32;
// output is FP32.
//
// Round 9:
//  - GEMM: software-pipelined REGISTER staging (buffer_load -> regs during the
//    MFMA phase of tile k, regs -> LDS at the top of tile k+1). The vmcnt wait
//    attaches to the ds_write, which executes a full MFMA phase after the loads
//    issue — hiding load latency that round-8's global_load_lds+barrier
//    structure serialized. LDS layout (XOR swizzle) byte-identical to round 6
//    (measured: 0 bank conflicts).
//  - Pre-pass: 16 elems/thread (4 independent 16B loads) for MLP; was 3 TB/s.

typedef __bf16 bf16x8 __attribute__((ext_vector_type(8)));
typedef float f32x4 __attribute__((ext_vector_type(4)));

#define BM 128
#define BN 128
#define BK 64

static __device__ __forceinline__ int pack_bf16x2(float a, float b) {
    __hip_bfloat162 p = __float22bfloat162_rn(make_float2(a, b));
    int r;
    __builtin_memcpy(&r, &p, 4);
    return r;
}

// ---------------- merged pre-pass: dequant Wq -> Wd  AND  x fp32 -> Ad ------
// blocks [0, nWBlocks): dequant (16 elems/thread);
// blocks [nWBlocks, nWBlocks+nABlocks): convert x (16 elems/thread).
__global__ __launch_bounds__(256) void prepass_kernel(
    const float* __restrict__ X,
    const int*   __restrict__ Wq,
    const float* __restrict__ scale,
    const float* __restrict__ zero,
    unsigned short* __restrict__ Ad,
    unsigned short* __restrict__ Wd,
    int K, int G, int GROUP, int nWBlocks)
{
    const int b = blockIdx.x;
    if (b < nWBlocks) {
        const unsigned int idx = (unsigned int)b * 256u + threadIdx.x;
        const unsigned int f = idx * 16u;             // N*K = 16.7M < 2^31
        const unsigned int n = f / (unsigned int)K;
        const unsigned int k = f - n * (unsigned int)K;
        const unsigned int g = k / (unsigned int)GROUP;   // 16 | GROUP
        const float s  = scale[(size_t)n * G + g];
        const float z  = zero [(size_t)n * G + g];
        const float mz = -z * s;                      // (q-z)*s == q*s + mz
        const int4 q0 = *(const int4*)(Wq + f);
        const int4 q1 = *(const int4*)(Wq + f + 4);
        const int4 q2 = *(const int4*)(Wq + f + 8);
        const int4 q3 = *(const int4*)(Wq + f + 12);
        int4 d0, d1;
        d0.x = pack_bf16x2((float)q0.x * s + mz, (float)q0.y * s + mz);
        d0.y = pack_bf16x2((float)q0.z * s + mz, (float)q0.w * s + mz);
        d0.z = pack_bf16x2((float)q1.x * s + mz, (float)q1.y * s + mz);
        d0.w = pack_bf16x2((float)q1.z * s + mz, (float)q1.w * s + mz);
        d1.x = pack_bf16x2((float)q2.x * s + mz, (float)q2.y * s + mz);
        d1.y = pack_bf16x2((float)q2.z * s + mz, (float)q2.w * s + mz);
        d1.z = pack_bf16x2((float)q3.x * s + mz, (float)q3.y * s + mz);
        d1.w = pack_bf16x2((float)q3.z * s + mz, (float)q3.w * s + mz);
        *(int4*)(Wd + f)     = d0;
        *(int4*)(Wd + f + 8) = d1;
    } else {
        const unsigned int idx = (unsigned int)(b - nWBlocks) * 256u + threadIdx.x;
        const unsigned int f = idx * 16u;             // M*K = 16.7M < 2^31
        const float4 a0 = *(const float4*)(X + f);
        const float4 a1 = *(const float4*)(X + f + 4);
        const float4 a2 = *(const float4*)(X + f + 8);
        const float4 a3 = *(const float4*)(X + f + 12);
        int4 d0, d1;
        d0.x = pack_bf16x2(a0.x, a0.y);
        d0.y = pack_bf16x2(a0.z, a0.w);
        d0.z = pack_bf16x2(a1.x, a1.y);
        d0.w = pack_bf16x2(a1.z, a1.w);
        d1.x = pack_bf16x2(a2.x, a2.y);
        d1.y = pack_bf16x2(a2.z, a2.w);
        d1.z = pack_bf16x2(a3.x, a3.y);
        d1.w = pack_bf16x2(a3.z, a3.w);
        *(int4*)(Ad + f)     = d0;
        *(int4*)(Ad + f + 8) = d1;
    }
}

// ---------------- GEMM: pipelined reg staging + XOR-swizzled LDS -----------
// C[M,N] = A[M,K] * Bw[N,K]^T + bias ; 256 threads = 4 waves in a 2x2 grid,
// each wave owns a 64x64 sub-tile = 4x4 grid of 16x16 MFMA tiles.
__global__ __launch_bounds__(256, 2) void gemm_bf16_nt(
    const unsigned short* __restrict__ A,     // bf16 bits [M,K]
    const unsigned short* __restrict__ Bw,    // bf16 bits [N,K]
    const float* __restrict__ bias,           // fp32 [N]
    float*       __restrict__ C,              // fp32 [M,N]
    int M, int N, int K)
{
    __shared__ unsigned short ldsA[BM * BK];   // 16 KB, swizzled row-major
    __shared__ unsigned short ldsB[BN * BK];   // 16 KB

    const int tid   = threadIdx.x;
    const int lane  = tid & 63;
    const int wave  = tid >> 6;
    const int waveM = wave >> 1;   // 0..1
    const int waveN = wave & 1;    // 0..1

    const int blockN0 = blockIdx.x * BN;
    const int blockM0 = blockIdx.y * BM;

    const long long aBase = (long long)blockM0 * K;
    const long long bBase = (long long)blockN0 * K;

    // staging geometry: thread t handles chunks {t, t+256, t+512, t+768};
    // chunk -> row = chunk>>3 (= c*32 + t>>3), global col-chunk gc = t&7.
    // LDS layout (round-6 XOR swizzle, measured 0 conflicts):
    //   row r, slot j holds global chunk j ^ (r&7)
    // so thread t stores its data at slot (t&7) ^ ((t>>3)&7).
    const int trow = tid >> 3;              // 0..31 (row within 32-row band)
    const int tgc  = tid & 7;               // global col chunk
    const int tsw  = tgc ^ (trow & 7);      // swizzled LDS slot

    f32x4 acc[4][4];
#pragma unroll
    for (int i = 0; i < 4; ++i)
#pragma unroll
        for (int j = 0; j < 4; ++j)
            acc[i][j] = (f32x4){0.f, 0.f, 0.f, 0.f};

    const int row16 = lane & 15;        // m/n index within a 16x16 tile
    const int quad  = lane >> 4;        // 0..3
    const int sw    = row16 & 7;        // reader-side swizzle term

    // ---- preload tile 0 into registers ----
    int4 ra[4], rb[4];
#pragma unroll
    for (int c = 0; c < 4; ++c) {
        const long long r = (long long)(c * 32 + trow) * K + tgc * 8;
        ra[c] = *(const int4*)(A  + aBase + r);
        rb[c] = *(const int4*)(Bw + bBase + r);
    }

    for (int k0 = 0; k0 < K; k0 += BK) {
        __syncthreads();   // previous tile's readers done; LDS free
        // ---- regs -> LDS (vmcnt wait for the prefetch lands HERE, a full
        //      MFMA phase after the loads were issued) ----
#pragma unroll
        for (int c = 0; c < 4; ++c) {
            const int ofs = (c * 32 + trow) * BK + tsw * 8;
            *(int4*)&ldsA[ofs] = ra[c];
            *(int4*)&ldsB[ofs] = rb[c];
        }
        __syncthreads();   // tile ready

        // ---- issue prefetch for tile k0+BK (consumed next iteration) ----
        if (k0 + BK < K) {
            const long long kn = k0 + BK;
#pragma unroll
            for (int c = 0; c < 4; ++c) {
                const long long r = (long long)(c * 32 + trow) * K + kn + tgc * 8;
                ra[c] = *(const int4*)(A  + aBase + r);
                rb[c] = *(const int4*)(Bw + bBase + r);
            }
        }

        // ---- compute: two k-steps of 32 (prefetch in flight) ----
#pragma unroll
        for (int kk = 0; kk < 2; ++kk) {
            bf16x8 av[4], bv[4];
            const int slot = (kk * 4 + quad) ^ sw;          // swizzled read
#pragma unroll
            for (int i = 0; i < 4; ++i) {
                const int r = waveM * 64 + i * 16 + row16;
                av[i] = *(const bf16x8*)&ldsA[r * BK + slot * 8];
            }
#pragma unroll
            for (int j = 0; j < 4; ++j) {
                const int r = waveN * 64 + j * 16 + row16;
                bv[j] = *(const bf16x8*)&ldsB[r * BK + slot * 8];
            }
#pragma unroll
            for (int i = 0; i < 4; ++i)
#pragma unroll
                for (int j = 0; j < 4; ++j)
                    acc[i][j] = __builtin_amdgcn_mfma_f32_16x16x32_bf16(
                        av[i], bv[j], acc[i][j], 0, 0, 0);
        }
    }

    // ---- epilogue: C/D layout col=lane&15, row=quad*4+reg  [m89-verified] ----
    const int colBase = blockN0 + waveN * 64;
    const int rowBase = blockM0 + waveM * 64;
    float biasf[4];
#pragma unroll
    for (int j = 0; j < 4; ++j)
        biasf[j] = bias[colBase + j * 16 + row16];

#pragma unroll
    for (int i = 0; i < 4; ++i) {
        const int row0 = rowBase + i * 16 + quad * 4;
#pragma unroll
        for (int j = 0; j < 4; ++j) {
            const int col = colBase + j * 16 + row16;
#pragma unroll
            for (int r = 0; r < 4; ++r) {
                C[(long long)(row0 + r) * N + col] = acc[i][j][r] + biasf[j];
            }
        }
    }
}

// ---------------- fallback: fused kernel (no workspace) ---------------------
__global__ __launch_bounds__(256) void hqq_gemm_fused_f32(
    const float* __restrict__ A,
    const int*   __restrict__ Wq,
    const float* __restrict__ scale,
    const float* __restrict__ zero,
    const float* __restrict__ bias,
    float*       __restrict__ C,
    int M, int N, int K, int G, int GROUP)
{
    __shared__ unsigned short ldsA[BM * BK];
    __shared__ unsigned short ldsB[BN * BK];

    const int tid   = threadIdx.x;
    const int lane  = tid & 63;
    const int wave  = tid >> 6;
    const int waveM = wave >> 1;
    const int waveN = wave & 1;

    const int blockN0 = blockIdx.x * BN;
    const int blockM0 = blockIdx.y * BM;

    const int row16 = lane & 15;
    const int quad  = lane >> 4;

    f32x4 acc[4][4];
#pragma unroll
    for (int i = 0; i < 4; ++i)
#pragma unroll
        for (int j = 0; j < 4; ++j)
            acc[i][j] = (f32x4){0.f, 0.f, 0.f, 0.f};

    for (int k0 = 0; k0 < K; k0 += BK) {
        const int g = k0 / GROUP;
        int4 ra[4], rb[4];
#pragma unroll
        for (int c = 0; c < 4; ++c) {
            const int chunk = c * 256 + tid;
            const int row   = chunk >> 3;
            const int col   = (chunk & 7) * 8;

            const float* ap = A + (long long)(blockM0 + row) * K + k0 + col;
            const float4 a0 = *(const float4*)(ap);
            const float4 a1 = *(const float4*)(ap + 4);
            int4 da;
            da.x = pack_bf16x2(a0.x, a0.y);
            da.y = pack_bf16x2(a0.z, a0.w);
            da.z = pack_bf16x2(a1.x, a1.y);
            da.w = pack_bf16x2(a1.z, a1.w);
            ra[c] = da;

            const int n = blockN0 + row;
            const float s  = scale[(long long)n * G + g];
            const float z  = zero [(long long)n * G + g];
            const float mz = -z * s;
            const long long wb = (long long)n * K + k0 + col;
            const int4 q0 = *(const int4*)(Wq + wb);
            const int4 q1 = *(const int4*)(Wq + wb + 4);
            int4 db;
            db.x = pack_bf16x2((float)q0.x * s + mz, (float)q0.y * s + mz);
            db.y = pack_bf16x2((float)q0.z * s + mz, (float)q0.w * s + mz);
            db.z = pack_bf16x2((float)q1.x * s + mz, (float)q1.y * s + mz);
            db.w = pack_bf16x2((float)q1.z * s + mz, (float)q1.w * s + mz);
            rb[c] = db;
        }

        __syncthreads();
#pragma unroll
        for (int c = 0; c < 4; ++c) {
            const int chunk = c * 256 + tid;
            *(int4*)&ldsA[chunk * 8] = ra[c];
            *(int4*)&ldsB[chunk * 8] = rb[c];
        }
        __syncthreads();

#pragma unroll
        for (int kk = 0; kk < 2; ++kk) {
            const int kOff = kk * 32 + quad * 8;
            bf16x8 av[4], bv[4];
#pragma unroll
            for (int i = 0; i < 4; ++i)
                av[i] = *(const bf16x8*)&ldsA[(waveM * 64 + i * 16 + row16) * BK + kOff];
#pragma unroll
            for (int j = 0; j < 4; ++j)
                bv[j] = *(const bf16x8*)&ldsB[(waveN * 64 + j * 16 + row16) * BK + kOff];
#pragma unroll
            for (int i = 0; i < 4; ++i)
#pragma unroll
                for (int j = 0; j < 4; ++j)
                    acc[i][j] = __builtin_amdgcn_mfma_f32_16x16x32_bf16(
                        av[i], bv[j], acc[i][j], 0, 0, 0);
        }
    }

    const int colBase = blockN0 + waveN * 64;
    const int rowBase = blockM0 + waveM * 64;
    float biasf[4];
#pragma unroll
    for (int j = 0; j < 4; ++j)
        biasf[j] = bias[colBase + j * 16 + row16];

#pragma unroll
    for (int i = 0; i < 4; ++i) {
        const int row0 = rowBase + i * 16 + quad * 4;
#pragma unroll
        for (int j = 0; j < 4; ++j) {
            const int col = colBase + j * 16 + row16;
#pragma unroll
            for (int r = 0; r < 4; ++r) {
                C[(long long)(row0 + r) * N + col] = acc[i][j][r] + biasf[j];
            }
        }
    }
}

extern "C" void kernel_launch(void* const* d_in, const int* in_sizes, int n_in,
                              void* d_out, int out_size, void* d_ws, size_t ws_size,
                              hipStream_t stream) {
    (void)n_in; (void)out_size;

    const float* x     = (const float*)d_in[0];
    const int*   Wq    = (const int*)d_in[1];
    const float* scale = (const float*)d_in[2];
    const float* zero  = (const float*)d_in[3];
    const float* bias  = (const float*)d_in[4];
    float*       out   = (float*)d_out;

    const int N     = in_sizes[4];            // 4096
    const int G     = in_sizes[2] / N;        // 32
    const int K     = in_sizes[1] / N;        // 4096
    const int M     = in_sizes[0] / K;        // 4096 (B*S)
    const int GROUP = K / G;                  // 128

    const size_t needWs = (size_t)N * K * 2 + (size_t)M * K * 2;  // 64 MB

    if (ws_size >= needWs) {
        unsigned short* Wd = (unsigned short*)d_ws;                        // [N,K] bf16
        unsigned short* Ad = (unsigned short*)((char*)d_ws + (size_t)N * K * 2);  // [M,K] bf16

        const int nWBlocks = (int)((long long)N * K / 16 / 256);
        const int nABlocks = (int)((long long)M * K / 16 / 256);
        prepass_kernel<<<nWBlocks + nABlocks, 256, 0, stream>>>(
            x, Wq, scale, zero, Ad, Wd, K, G, GROUP, nWBlocks);

        dim3 grid(N / BN, M / BM);
        gemm_bf16_nt<<<grid, 256, 0, stream>>>(Ad, Wd, bias, out, M, N, K);
    } else {
        dim3 grid(N / BN, M / BM);
        hqq_gemm_fused_f32<<<grid, 256, 0, stream>>>(x, Wq, scale, zero, bias, out,
                                                     M, N, K, G, GROUP);
    }
}

// Round 10
// 315.982 us; speedup vs baseline: 2.4117x; 2.4117x over previous
//
#include <hip/hip_runtime.h>
#include <hip/hip_bf16.h>

// HQQ 4-bit linear: out = x @ dequant(W_q)^T + bias
// M=B*S=4096, K=4096, N=4096, GROUP=128. fp16 reference arrays arrive as FP32;
// output is FP32.
//
// Round 10: round-9 pipeline with the register spill fixed. Round 9's counters
// showed the compiler spilled the int4 ra[4]/rb[4] prefetch arrays to scratch
// (WRITE_SIZE 2.16 GB == 128B x 256thr x 64iter x 1024blk exactly) while
// pinning VGPR_Count at 64 (the 8-wave occupancy breakpoint). Fix: eight
// individual int4 scalars (no arrays -> SROA-proof) + __launch_bounds__(256,1)
// so the allocator may exceed 64 VGPRs. Pipeline, XOR swizzle (0 conflicts),
// MFMA shape, epilogue, and merged pre-pass are unchanged from round 9.

typedef __bf16 bf16x8 __attribute__((ext_vector_type(8)));
typedef float f32x4 __attribute__((ext_vector_type(4)));

#define BM 128
#define BN 128
#define BK 64

static __device__ __forceinline__ int pack_bf16x2(float a, float b) {
    __hip_bfloat162 p = __float22bfloat162_rn(make_float2(a, b));
    int r;
    __builtin_memcpy(&r, &p, 4);
    return r;
}

// ---------------- merged pre-pass: dequant Wq -> Wd  AND  x fp32 -> Ad ------
// blocks [0, nWBlocks): dequant (16 elems/thread);
// blocks [nWBlocks, nWBlocks+nABlocks): convert x (16 elems/thread).
__global__ __launch_bounds__(256) void prepass_kernel(
    const float* __restrict__ X,
    const int*   __restrict__ Wq,
    const float* __restrict__ scale,
    const float* __restrict__ zero,
    unsigned short* __restrict__ Ad,
    unsigned short* __restrict__ Wd,
    int K, int G, int GROUP, int nWBlocks)
{
    const int b = blockIdx.x;
    if (b < nWBlocks) {
        const unsigned int idx = (unsigned int)b * 256u + threadIdx.x;
        const unsigned int f = idx * 16u;             // N*K = 16.7M < 2^31
        const unsigned int n = f / (unsigned int)K;
        const unsigned int k = f - n * (unsigned int)K;
        const unsigned int g = k / (unsigned int)GROUP;   // 16 | GROUP
        const float s  = scale[(size_t)n * G + g];
        const float z  = zero [(size_t)n * G + g];
        const float mz = -z * s;                      // (q-z)*s == q*s + mz
        const int4 q0 = *(const int4*)(Wq + f);
        const int4 q1 = *(const int4*)(Wq + f + 4);
        const int4 q2 = *(const int4*)(Wq + f + 8);
        const int4 q3 = *(const int4*)(Wq + f + 12);
        int4 d0, d1;
        d0.x = pack_bf16x2((float)q0.x * s + mz, (float)q0.y * s + mz);
        d0.y = pack_bf16x2((float)q0.z * s + mz, (float)q0.w * s + mz);
        d0.z = pack_bf16x2((float)q1.x * s + mz, (float)q1.y * s + mz);
        d0.w = pack_bf16x2((float)q1.z * s + mz, (float)q1.w * s + mz);
        d1.x = pack_bf16x2((float)q2.x * s + mz, (float)q2.y * s + mz);
        d1.y = pack_bf16x2((float)q2.z * s + mz, (float)q2.w * s + mz);
        d1.z = pack_bf16x2((float)q3.x * s + mz, (float)q3.y * s + mz);
        d1.w = pack_bf16x2((float)q3.z * s + mz, (float)q3.w * s + mz);
        *(int4*)(Wd + f)     = d0;
        *(int4*)(Wd + f + 8) = d1;
    } else {
        const unsigned int idx = (unsigned int)(b - nWBlocks) * 256u + threadIdx.x;
        const unsigned int f = idx * 16u;             // M*K = 16.7M < 2^31
        const float4 a0 = *(const float4*)(X + f);
        const float4 a1 = *(const float4*)(X + f + 4);
        const float4 a2 = *(const float4*)(X + f + 8);
        const float4 a3 = *(const float4*)(X + f + 12);
        int4 d0, d1;
        d0.x = pack_bf16x2(a0.x, a0.y);
        d0.y = pack_bf16x2(a0.z, a0.w);
        d0.z = pack_bf16x2(a1.x, a1.y);
        d0.w = pack_bf16x2(a1.z, a1.w);
        d1.x = pack_bf16x2(a2.x, a2.y);
        d1.y = pack_bf16x2(a2.z, a2.w);
        d1.z = pack_bf16x2(a3.x, a3.y);
        d1.w = pack_bf16x2(a3.z, a3.w);
        *(int4*)(Ad + f)     = d0;
        *(int4*)(Ad + f + 8) = d1;
    }
}

// ---------------- GEMM: pipelined reg staging + XOR-swizzled LDS -----------
// C[M,N] = A[M,K] * Bw[N,K]^T + bias ; 256 threads = 4 waves in a 2x2 grid,
// each wave owns a 64x64 sub-tile = 4x4 grid of 16x16 MFMA tiles.
__global__ __launch_bounds__(256, 1) void gemm_bf16_nt(
    const unsigned short* __restrict__ A,     // bf16 bits [M,K]
    const unsigned short* __restrict__ Bw,    // bf16 bits [N,K]
    const float* __restrict__ bias,           // fp32 [N]
    float*       __restrict__ C,              // fp32 [M,N]
    int M, int N, int K)
{
    __shared__ unsigned short ldsA[BM * BK];   // 16 KB, swizzled row-major
    __shared__ unsigned short ldsB[BN * BK];   // 16 KB

    const int tid   = threadIdx.x;
    const int lane  = tid & 63;
    const int wave  = tid >> 6;
    const int waveM = wave >> 1;   // 0..1
    const int waveN = wave & 1;    // 0..1

    const int blockN0 = blockIdx.x * BN;
    const int blockM0 = blockIdx.y * BM;

    // staging geometry: thread t handles rows {trow, trow+32, trow+64, trow+96}
    // with global col-chunk gc = t&7; LDS layout (round-6 XOR swizzle,
    // measured 0 conflicts): row r, slot j holds global chunk j ^ (r&7),
    // so thread t stores at slot (t&7) ^ ((t>>3)&7).
    const int trow = tid >> 3;              // 0..31
    const int tgc  = tid & 7;               // global col chunk
    const int tsw  = tgc ^ (trow & 7);      // swizzled LDS slot

    const long long rowStride32 = 32LL * K;
    const unsigned short* aP = A  + (long long)(blockM0 + trow) * K + tgc * 8;
    const unsigned short* bP = Bw + (long long)(blockN0 + trow) * K + tgc * 8;

    const int stBase = trow * BK + tsw * 8;   // LDS elem offset for chunk 0

    f32x4 acc[4][4];
#pragma unroll
    for (int i = 0; i < 4; ++i)
#pragma unroll
        for (int j = 0; j < 4; ++j)
            acc[i][j] = (f32x4){0.f, 0.f, 0.f, 0.f};

    const int row16 = lane & 15;        // m/n index within a 16x16 tile
    const int quad  = lane >> 4;        // 0..3
    const int sw    = row16 & 7;        // reader-side swizzle term

    // ---- preload tile 0 into individual scalar registers (SROA-proof) ----
    int4 ra0 = *(const int4*)(aP);
    int4 ra1 = *(const int4*)(aP + rowStride32);
    int4 ra2 = *(const int4*)(aP + 2 * rowStride32);
    int4 ra3 = *(const int4*)(aP + 3 * rowStride32);
    int4 rb0 = *(const int4*)(bP);
    int4 rb1 = *(const int4*)(bP + rowStride32);
    int4 rb2 = *(const int4*)(bP + 2 * rowStride32);
    int4 rb3 = *(const int4*)(bP + 3 * rowStride32);

    for (int k0 = 0; k0 < K; k0 += BK) {
        __syncthreads();   // previous tile's readers done; LDS free
        // ---- regs -> LDS (prefetch vmcnt wait lands here, one full MFMA
        //      phase after the loads were issued) ----
        *(int4*)&ldsA[stBase]             = ra0;
        *(int4*)&ldsA[stBase + 32 * BK]   = ra1;
        *(int4*)&ldsA[stBase + 64 * BK]   = ra2;
        *(int4*)&ldsA[stBase + 96 * BK]   = ra3;
        *(int4*)&ldsB[stBase]             = rb0;
        *(int4*)&ldsB[stBase + 32 * BK]   = rb1;
        *(int4*)&ldsB[stBase + 64 * BK]   = rb2;
        *(int4*)&ldsB[stBase + 96 * BK]   = rb3;
        __syncthreads();   // tile ready

        // ---- issue prefetch for tile k0+BK (consumed next iteration) ----
        if (k0 + BK < K) {
            const unsigned short* aN = aP + k0 + BK;
            const unsigned short* bN = bP + k0 + BK;
            ra0 = *(const int4*)(aN);
            ra1 = *(const int4*)(aN + rowStride32);
            ra2 = *(const int4*)(aN + 2 * rowStride32);
            ra3 = *(const int4*)(aN + 3 * rowStride32);
            rb0 = *(const int4*)(bN);
            rb1 = *(const int4*)(bN + rowStride32);
            rb2 = *(const int4*)(bN + 2 * rowStride32);
            rb3 = *(const int4*)(bN + 3 * rowStride32);
        }

        // ---- compute: two k-steps of 32 (prefetch in flight) ----
#pragma unroll
        for (int kk = 0; kk < 2; ++kk) {
            bf16x8 av[4], bv[4];
            const int slot = (kk * 4 + quad) ^ sw;          // swizzled read
#pragma unroll
            for (int i = 0; i < 4; ++i) {
                const int r = waveM * 64 + i * 16 + row16;
                av[i] = *(const bf16x8*)&ldsA[r * BK + slot * 8];
            }
#pragma unroll
            for (int j = 0; j < 4; ++j) {
                const int r = waveN * 64 + j * 16 + row16;
                bv[j] = *(const bf16x8*)&ldsB[r * BK + slot * 8];
            }
#pragma unroll
            for (int i = 0; i < 4; ++i)
#pragma unroll
                for (int j = 0; j < 4; ++j)
                    acc[i][j] = __builtin_amdgcn_mfma_f32_16x16x32_bf16(
                        av[i], bv[j], acc[i][j], 0, 0, 0);
        }
    }

    // ---- epilogue: C/D layout col=lane&15, row=quad*4+reg  [m89-verified] ----
    const int colBase = blockN0 + waveN * 64;
    const int rowBase = blockM0 + waveM * 64;
    float biasf[4];
#pragma unroll
    for (int j = 0; j < 4; ++j)
        biasf[j] = bias[colBase + j * 16 + row16];

#pragma unroll
    for (int i = 0; i < 4; ++i) {
        const int row0 = rowBase + i * 16 + quad * 4;
#pragma unroll
        for (int j = 0; j < 4; ++j) {
            const int col = colBase + j * 16 + row16;
#pragma unroll
            for (int r = 0; r < 4; ++r) {
                C[(long long)(row0 + r) * N + col] = acc[i][j][r] + biasf[j];
            }
        }
    }
}

// ---------------- fallback: fused kernel (no workspace) ---------------------
__global__ __launch_bounds__(256) void hqq_gemm_fused_f32(
    const float* __restrict__ A,
    const int*   __restrict__ Wq,
    const float* __restrict__ scale,
    const float* __restrict__ zero,
    const float* __restrict__ bias,
    float*       __restrict__ C,
    int M, int N, int K, int G, int GROUP)
{
    __shared__ unsigned short ldsA[BM * BK];
    __shared__ unsigned short ldsB[BN * BK];

    const int tid   = threadIdx.x;
    const int lane  = tid & 63;
    const int wave  = tid >> 6;
    const int waveM = wave >> 1;
    const int waveN = wave & 1;

    const int blockN0 = blockIdx.x * BN;
    const int blockM0 = blockIdx.y * BM;

    const int row16 = lane & 15;
    const int quad  = lane >> 4;

    f32x4 acc[4][4];
#pragma unroll
    for (int i = 0; i < 4; ++i)
#pragma unroll
        for (int j = 0; j < 4; ++j)
            acc[i][j] = (f32x4){0.f, 0.f, 0.f, 0.f};

    for (int k0 = 0; k0 < K; k0 += BK) {
        const int g = k0 / GROUP;
        int4 ra[4], rb[4];
#pragma unroll
        for (int c = 0; c < 4; ++c) {
            const int chunk = c * 256 + tid;
            const int row   = chunk >> 3;
            const int col   = (chunk & 7) * 8;

            const float* ap = A + (long long)(blockM0 + row) * K + k0 + col;
            const float4 a0 = *(const float4*)(ap);
            const float4 a1 = *(const float4*)(ap + 4);
            int4 da;
            da.x = pack_bf16x2(a0.x, a0.y);
            da.y = pack_bf16x2(a0.z, a0.w);
            da.z = pack_bf16x2(a1.x, a1.y);
            da.w = pack_bf16x2(a1.z, a1.w);
            ra[c] = da;

            const int n = blockN0 + row;
            const float s  = scale[(long long)n * G + g];
            const float z  = zero [(long long)n * G + g];
            const float mz = -z * s;
            const long long wb = (long long)n * K + k0 + col;
            const int4 q0 = *(const int4*)(Wq + wb);
            const int4 q1 = *(const int4*)(Wq + wb + 4);
            int4 db;
            db.x = pack_bf16x2((float)q0.x * s + mz, (float)q0.y * s + mz);
            db.y = pack_bf16x2((float)q0.z * s + mz, (float)q0.w * s + mz);
            db.z = pack_bf16x2((float)q1.x * s + mz, (float)q1.y * s + mz);
            db.w = pack_bf16x2((float)q1.z * s + mz, (float)q1.w * s + mz);
            rb[c] = db;
        }

        __syncthreads();
#pragma unroll
        for (int c = 0; c < 4; ++c) {
            const int chunk = c * 256 + tid;
            *(int4*)&ldsA[chunk * 8] = ra[c];
            *(int4*)&ldsB[chunk * 8] = rb[c];
        }
        __syncthreads();

#pragma unroll
        for (int kk = 0; kk < 2; ++kk) {
            const int kOff = kk * 32 + quad * 8;
            bf16x8 av[4], bv[4];
#pragma unroll
            for (int i = 0; i < 4; ++i)
                av[i] = *(const bf16x8*)&ldsA[(waveM * 64 + i * 16 + row16) * BK + kOff];
#pragma unroll
            for (int j = 0; j < 4; ++j)
                bv[j] = *(const bf16x8*)&ldsB[(waveN * 64 + j * 16 + row16) * BK + kOff];
#pragma unroll
            for (int i = 0; i < 4; ++i)
#pragma unroll
                for (int j = 0; j < 4; ++j)
                    acc[i][j] = __builtin_amdgcn_mfma_f32_16x16x32_bf16(
                        av[i], bv[j], acc[i][j], 0, 0, 0);
        }
    }

    const int colBase = blockN0 + waveN * 64;
    const int rowBase = blockM0 + waveM * 64;
    float biasf[4];
#pragma unroll
    for (int j = 0; j < 4; ++j)
        biasf[j] = bias[colBase + j * 16 + row16];

#pragma unroll
    for (int i = 0; i < 4; ++i) {
        const int row0 = rowBase + i * 16 + quad * 4;
#pragma unroll
        for (int j = 0; j < 4; ++j) {
            const int col = colBase + j * 16 + row16;
#pragma unroll
            for (int r = 0; r < 4; ++r) {
                C[(long long)(row0 + r) * N + col] = acc[i][j][r] + biasf[j];
            }
        }
    }
}

extern "C" void kernel_launch(void* const* d_in, const int* in_sizes, int n_in,
                              void* d_out, int out_size, void* d_ws, size_t ws_size,
                              hipStream_t stream) {
    (void)n_in; (void)out_size;

    const float* x     = (const float*)d_in[0];
    const int*   Wq    = (const int*)d_in[1];
    const float* scale = (const float*)d_in[2];
    const float* zero  = (const float*)d_in[3];
    const float* bias  = (const float*)d_in[4];
    float*       out   = (float*)d_out;

    const int N     = in_sizes[4];            // 4096
    const int G     = in_sizes[2] / N;        // 32
    const int K     = in_sizes[1] / N;        // 4096
    const int M     = in_sizes[0] / K;        // 4096 (B*S)
    const int GROUP = K / G;                  // 128

    const size_t needWs = (size_t)N * K * 2 + (size_t)M * K * 2;  // 64 MB

    if (ws_size >= needWs) {
        unsigned short* Wd = (unsigned short*)d_ws;                        // [N,K] bf16
        unsigned short* Ad = (unsigned short*)((char*)d_ws + (size_t)N * K * 2);  // [M,K] bf16

        const int nWBlocks = (int)((long long)N * K / 16 / 256);
        const int nABlocks = (int)((long long)M * K / 16 / 256);
        prepass_kernel<<<nWBlocks + nABlocks, 256, 0, stream>>>(
            x, Wq, scale, zero, Ad, Wd, K, G, GROUP, nWBlocks);

        dim3 grid(N / BN, M / BM);
        gemm_bf16_nt<<<grid, 256, 0, stream>>>(Ad, Wd, bias, out, M, N, K);
    } else {
        dim3 grid(N / BN, M / BM);
        hqq_gemm_fused_f32<<<grid, 256, 0, stream>>>(x, Wq, scale, zero, bias, out,
                                                     M, N, K, G, GROUP);
    }
}

// Round 11
// 295.645 us; speedup vs baseline: 2.5776x; 1.0688x over previous
//
#include <hip/hip_runtime.h>
#include <hip/hip_bf16.h>

// HQQ 4-bit linear: out = x @ dequant(W_q)^T + bias
// M=B*S=4096, K=4096, N=4096, GROUP=128. fp16 reference arrays arrive as FP32;
// output is FP32.
//
// Round 11: consolidation of best-measured components.
//  - GEMM: round-8 structure exactly (16x16x32 bf16 MFMA, 4x4 acc/wave,
//    128x128 tile, BK=64, global_load_lds width-16, XOR-swizzled LDS,
//    launch_bounds(256,2)): measured 131 us, MfmaUtil 51%, 0 bank conflicts.
//    Pipelining attempts (rounds 9/10: reg-staging prefetch) regressed
//    (161-600 us) — the implicit multi-wave overlap at 8-wave occupancy IS
//    the best pipeline for this K-loop shape; do not reintroduce.
//  - Pre-pass: merged single dispatch, 16 elems/thread (round 10: ~51 us vs
//    65 us for 8-elem).

typedef __bf16 bf16x8 __attribute__((ext_vector_type(8)));
typedef float f32x4 __attribute__((ext_vector_type(4)));

#define BM 128
#define BN 128
#define BK 64

static __device__ __forceinline__ int pack_bf16x2(float a, float b) {
    __hip_bfloat162 p = __float22bfloat162_rn(make_float2(a, b));
    int r;
    __builtin_memcpy(&r, &p, 4);
    return r;
}

// ---------------- merged pre-pass: dequant Wq -> Wd  AND  x fp32 -> Ad ------
// blocks [0, nWBlocks): dequant (16 elems/thread);
// blocks [nWBlocks, nWBlocks+nABlocks): convert x (16 elems/thread).
__global__ __launch_bounds__(256) void prepass_kernel(
    const float* __restrict__ X,
    const int*   __restrict__ Wq,
    const float* __restrict__ scale,
    const float* __restrict__ zero,
    unsigned short* __restrict__ Ad,
    unsigned short* __restrict__ Wd,
    int K, int G, int GROUP, int nWBlocks)
{
    const int b = blockIdx.x;
    if (b < nWBlocks) {
        const unsigned int idx = (unsigned int)b * 256u + threadIdx.x;
        const unsigned int f = idx * 16u;             // N*K = 16.7M < 2^31
        const unsigned int n = f / (unsigned int)K;
        const unsigned int k = f - n * (unsigned int)K;
        const unsigned int g = k / (unsigned int)GROUP;   // 16 | GROUP
        const float s  = scale[(size_t)n * G + g];
        const float z  = zero [(size_t)n * G + g];
        const float mz = -z * s;                      // (q-z)*s == q*s + mz
        const int4 q0 = *(const int4*)(Wq + f);
        const int4 q1 = *(const int4*)(Wq + f + 4);
        const int4 q2 = *(const int4*)(Wq + f + 8);
        const int4 q3 = *(const int4*)(Wq + f + 12);
        int4 d0, d1;
        d0.x = pack_bf16x2((float)q0.x * s + mz, (float)q0.y * s + mz);
        d0.y = pack_bf16x2((float)q0.z * s + mz, (float)q0.w * s + mz);
        d0.z = pack_bf16x2((float)q1.x * s + mz, (float)q1.y * s + mz);
        d0.w = pack_bf16x2((float)q1.z * s + mz, (float)q1.w * s + mz);
        d1.x = pack_bf16x2((float)q2.x * s + mz, (float)q2.y * s + mz);
        d1.y = pack_bf16x2((float)q2.z * s + mz, (float)q2.w * s + mz);
        d1.z = pack_bf16x2((float)q3.x * s + mz, (float)q3.y * s + mz);
        d1.w = pack_bf16x2((float)q3.z * s + mz, (float)q3.w * s + mz);
        *(int4*)(Wd + f)     = d0;
        *(int4*)(Wd + f + 8) = d1;
    } else {
        const unsigned int idx = (unsigned int)(b - nWBlocks) * 256u + threadIdx.x;
        const unsigned int f = idx * 16u;             // M*K = 16.7M < 2^31
        const float4 a0 = *(const float4*)(X + f);
        const float4 a1 = *(const float4*)(X + f + 4);
        const float4 a2 = *(const float4*)(X + f + 8);
        const float4 a3 = *(const float4*)(X + f + 12);
        int4 d0, d1;
        d0.x = pack_bf16x2(a0.x, a0.y);
        d0.y = pack_bf16x2(a0.z, a0.w);
        d0.z = pack_bf16x2(a1.x, a1.y);
        d0.w = pack_bf16x2(a1.z, a1.w);
        d1.x = pack_bf16x2(a2.x, a2.y);
        d1.y = pack_bf16x2(a2.z, a2.w);
        d1.z = pack_bf16x2(a3.x, a3.y);
        d1.w = pack_bf16x2(a3.z, a3.w);
        *(int4*)(Ad + f)     = d0;
        *(int4*)(Ad + f + 8) = d1;
    }
}

// ---------------- GEMM kernel (round-8: m97 structure + XOR swizzle) -------
// C[M,N] = A[M,K] * Bw[N,K]^T + bias ; 256 threads = 4 waves in a 2x2 grid,
// each wave owns a 64x64 sub-tile = 4x4 grid of 16x16 MFMA tiles.
// [measured: 131 us, MfmaUtil 51%, SQ_LDS_BANK_CONFLICT 0, VGPR 64]
__global__ __launch_bounds__(256, 2) void gemm_bf16_nt(
    const unsigned short* __restrict__ A,     // bf16 bits [M,K]
    const unsigned short* __restrict__ Bw,    // bf16 bits [N,K]
    const float* __restrict__ bias,           // fp32 [N]
    float*       __restrict__ C,              // fp32 [M,N]
    int M, int N, int K)
{
    __shared__ unsigned short ldsA[BM * BK];   // 16 KB, swizzled row-major
    __shared__ unsigned short ldsB[BN * BK];   // 16 KB

    const int tid   = threadIdx.x;
    const int lane  = tid & 63;
    const int wave  = tid >> 6;
    const int waveM = wave >> 1;   // 0..1
    const int waveN = wave & 1;    // 0..1

    const int blockN0 = blockIdx.x * BN;
    const int blockM0 = blockIdx.y * BM;

    const long long aBase = (long long)blockM0 * K;
    const long long bBase = (long long)blockN0 * K;

    // staging: 16 chunks x (8 rows x 64 cols); each wave owns 4 chunks.
    // HW lane->LDS mapping: elem ofs = chunk*512 + lane*8. Lane l covers
    // row l>>3 of the chunk; it FETCHES global col chunk (l&7)^(l>>3), so
    // LDS row r slot j holds global chunk j ^ (r&7)   [XOR swizzle].
    const int rowInChunk = lane >> 3;
    const int col8       = ((lane & 7) ^ rowInChunk) * 8;

    f32x4 acc[4][4];
#pragma unroll
    for (int i = 0; i < 4; ++i)
#pragma unroll
        for (int j = 0; j < 4; ++j)
            acc[i][j] = (f32x4){0.f, 0.f, 0.f, 0.f};

    const int row16 = lane & 15;        // m/n index within a 16x16 tile
    const int quad  = lane >> 4;        // 0..3
    const int sw    = row16 & 7;        // reader-side swizzle term

    for (int k0 = 0; k0 < K; k0 += BK) {
        __syncthreads();   // protect LDS from previous iteration's readers
#pragma unroll
        for (int c = 0; c < 4; ++c) {
            const int chunk = (wave << 2) | c;              // 0..15, wave-uniform
            const int row   = (chunk << 3) | rowInChunk;    // 0..127
            const unsigned short* gA = A  + aBase + (long long)row * K + k0 + col8;
            const unsigned short* gB = Bw + bBase + (long long)row * K + k0 + col8;
            __builtin_amdgcn_global_load_lds(
                (const __attribute__((address_space(1))) unsigned int*)gA,
                (__attribute__((address_space(3))) unsigned int*)&ldsA[chunk * 512],
                16, 0, 0);
            __builtin_amdgcn_global_load_lds(
                (const __attribute__((address_space(1))) unsigned int*)gB,
                (__attribute__((address_space(3))) unsigned int*)&ldsB[chunk * 512],
                16, 0, 0);
        }
        __syncthreads();   // LDS tile ready

        // ---- compute: two k-steps of 32 ----
#pragma unroll
        for (int kk = 0; kk < 2; ++kk) {
            bf16x8 av[4], bv[4];
            const int slot = (kk * 4 + quad) ^ sw;          // swizzled read
#pragma unroll
            for (int i = 0; i < 4; ++i) {
                const int r = waveM * 64 + i * 16 + row16;
                av[i] = *(const bf16x8*)&ldsA[r * BK + slot * 8];
            }
#pragma unroll
            for (int j = 0; j < 4; ++j) {
                const int r = waveN * 64 + j * 16 + row16;
                bv[j] = *(const bf16x8*)&ldsB[r * BK + slot * 8];
            }
#pragma unroll
            for (int i = 0; i < 4; ++i)
#pragma unroll
                for (int j = 0; j < 4; ++j)
                    acc[i][j] = __builtin_amdgcn_mfma_f32_16x16x32_bf16(
                        av[i], bv[j], acc[i][j], 0, 0, 0);
        }
    }

    // ---- epilogue: C/D layout col=lane&15, row=quad*4+reg  [m89-verified] ----
    const int colBase = blockN0 + waveN * 64;
    const int rowBase = blockM0 + waveM * 64;
    float biasf[4];
#pragma unroll
    for (int j = 0; j < 4; ++j)
        biasf[j] = bias[colBase + j * 16 + row16];

#pragma unroll
    for (int i = 0; i < 4; ++i) {
        const int row0 = rowBase + i * 16 + quad * 4;
#pragma unroll
        for (int j = 0; j < 4; ++j) {
            const int col = colBase + j * 16 + row16;
#pragma unroll
            for (int r = 0; r < 4; ++r) {
                C[(long long)(row0 + r) * N + col] = acc[i][j][r] + biasf[j];
            }
        }
    }
}

// ---------------- fallback: fused kernel (no workspace) ---------------------
__global__ __launch_bounds__(256) void hqq_gemm_fused_f32(
    const float* __restrict__ A,
    const int*   __restrict__ Wq,
    const float* __restrict__ scale,
    const float* __restrict__ zero,
    const float* __restrict__ bias,
    float*       __restrict__ C,
    int M, int N, int K, int G, int GROUP)
{
    __shared__ unsigned short ldsA[BM * BK];
    __shared__ unsigned short ldsB[BN * BK];

    const int tid   = threadIdx.x;
    const int lane  = tid & 63;
    const int wave  = tid >> 6;
    const int waveM = wave >> 1;
    const int waveN = wave & 1;

    const int blockN0 = blockIdx.x * BN;
    const int blockM0 = blockIdx.y * BM;

    const int row16 = lane & 15;
    const int quad  = lane >> 4;

    f32x4 acc[4][4];
#pragma unroll
    for (int i = 0; i < 4; ++i)
#pragma unroll
        for (int j = 0; j < 4; ++j)
            acc[i][j] = (f32x4){0.f, 0.f, 0.f, 0.f};

    for (int k0 = 0; k0 < K; k0 += BK) {
        const int g = k0 / GROUP;
        int4 ra[4], rb[4];
#pragma unroll
        for (int c = 0; c < 4; ++c) {
            const int chunk = c * 256 + tid;
            const int row   = chunk >> 3;
            const int col   = (chunk & 7) * 8;

            const float* ap = A + (long long)(blockM0 + row) * K + k0 + col;
            const float4 a0 = *(const float4*)(ap);
            const float4 a1 = *(const float4*)(ap + 4);
            int4 da;
            da.x = pack_bf16x2(a0.x, a0.y);
            da.y = pack_bf16x2(a0.z, a0.w);
            da.z = pack_bf16x2(a1.x, a1.y);
            da.w = pack_bf16x2(a1.z, a1.w);
            ra[c] = da;

            const int n = blockN0 + row;
            const float s  = scale[(long long)n * G + g];
            const float z  = zero [(long long)n * G + g];
            const float mz = -z * s;
            const long long wb = (long long)n * K + k0 + col;
            const int4 q0 = *(const int4*)(Wq + wb);
            const int4 q1 = *(const int4*)(Wq + wb + 4);
            int4 db;
            db.x = pack_bf16x2((float)q0.x * s + mz, (float)q0.y * s + mz);
            db.y = pack_bf16x2((float)q0.z * s + mz, (float)q0.w * s + mz);
            db.z = pack_bf16x2((float)q1.x * s + mz, (float)q1.y * s + mz);
            db.w = pack_bf16x2((float)q1.z * s + mz, (float)q1.w * s + mz);
            rb[c] = db;
        }

        __syncthreads();
#pragma unroll
        for (int c = 0; c < 4; ++c) {
            const int chunk = c * 256 + tid;
            *(int4*)&ldsA[chunk * 8] = ra[c];
            *(int4*)&ldsB[chunk * 8] = rb[c];
        }
        __syncthreads();

#pragma unroll
        for (int kk = 0; kk < 2; ++kk) {
            const int kOff = kk * 32 + quad * 8;
            bf16x8 av[4], bv[4];
#pragma unroll
            for (int i = 0; i < 4; ++i)
                av[i] = *(const bf16x8*)&ldsA[(waveM * 64 + i * 16 + row16) * BK + kOff];
#pragma unroll
            for (int j = 0; j < 4; ++j)
                bv[j] = *(const bf16x8*)&ldsB[(waveN * 64 + j * 16 + row16) * BK + kOff];
#pragma unroll
            for (int i = 0; i < 4; ++i)
#pragma unroll
                for (int j = 0; j < 4; ++j)
                    acc[i][j] = __builtin_amdgcn_mfma_f32_16x16x32_bf16(
                        av[i], bv[j], acc[i][j], 0, 0, 0);
        }
    }

    const int colBase = blockN0 + waveN * 64;
    const int rowBase = blockM0 + waveM * 64;
    float biasf[4];
#pragma unroll
    for (int j = 0; j < 4; ++j)
        biasf[j] = bias[colBase + j * 16 + row16];

#pragma unroll
    for (int i = 0; i < 4; ++i) {
        const int row0 = rowBase + i * 16 + quad * 4;
#pragma unroll
        for (int j = 0; j < 4; ++j) {
            const int col = colBase + j * 16 + row16;
#pragma unroll
            for (int r = 0; r < 4; ++r) {
                C[(long long)(row0 + r) * N + col] = acc[i][j][r] + biasf[j];
            }
        }
    }
}

extern "C" void kernel_launch(void* const* d_in, const int* in_sizes, int n_in,
                              void* d_out, int out_size, void* d_ws, size_t ws_size,
                              hipStream_t stream) {
    (void)n_in; (void)out_size;

    const float* x     = (const float*)d_in[0];
    const int*   Wq    = (const int*)d_in[1];
    const float* scale = (const float*)d_in[2];
    const float* zero  = (const float*)d_in[3];
    const float* bias  = (const float*)d_in[4];
    float*       out   = (float*)d_out;

    const int N     = in_sizes[4];            // 4096
    const int G     = in_sizes[2] / N;        // 32
    const int K     = in_sizes[1] / N;        // 4096
    const int M     = in_sizes[0] / K;        // 4096 (B*S)
    const int GROUP = K / G;                  // 128

    const size_t needWs = (size_t)N * K * 2 + (size_t)M * K * 2;  // 64 MB

    if (ws_size >= needWs) {
        unsigned short* Wd = (unsigned short*)d_ws;                        // [N,K] bf16
        unsigned short* Ad = (unsigned short*)((char*)d_ws + (size_t)N * K * 2);  // [M,K] bf16

        const int nWBlocks = (int)((long long)N * K / 16 / 256);
        const int nABlocks = (int)((long long)M * K / 16 / 256);
        prepass_kernel<<<nWBlocks + nABlocks, 256, 0, stream>>>(
            x, Wq, scale, zero, Ad, Wd, K, G, GROUP, nWBlocks);

        dim3 grid(N / BN, M / BM);
        gemm_bf16_nt<<<grid, 256, 0, stream>>>(Ad, Wd, bias, out, M, N, K);
    } else {
        dim3 grid(N / BN, M / BM);
        hqq_gemm_fused_f32<<<grid, 256, 0, stream>>>(x, Wq, scale, zero, bias, out,
                                                     M, N, K, G, GROUP);
    }
}